// Round 19
// baseline (691.008 us; speedup 1.0000x reference)
//
#include <hip/hip_runtime.h>
#include <hip/hip_bf16.h>
#include <hip/hip_fp16.h>

// ---------------------------------------------------------------------------
// Hetero-GCN (3 node types, 9 relations), 2 GraphConv layers + classifier.
// Round 18 (agg confirmed L2-miss-service bound; attack the ~110us of launch
// boundaries + redundant H traffic):
//  - ONE agg launch per layer (9 independent tasks, grid 112500; blocks in 3
//    contiguous src-group ranges to keep XCD-L2 plane sharing).
//  - ONE GEMM per dst plane (K=512/256/384, template<NS> pointer arrays):
//    single writer per plane -> all STORE, no ACC read-modify, biases summed
//    in-kernel. 22 compute launches -> 12.
//  - 9 A-slots, zero new workspace: P[6..8] overlay h2h (layer 1) / xh
//    (layer 2) regions, both dead in those phases.
// ---------------------------------------------------------------------------

#define NN 50000
#define EE 400000
#define NRG 4            // node ranges for src histogram
#define RGN (NN / NRG)   // 12500 nodes per range
#define HCH 16           // edge chunks
#define HEG (EE / HCH)   // 25000 edges per chunk
#define NBK 98           // dst buckets (dst>>9)
#define BKW 512          // dsts per bucket
#define CH1 8192         // bucket pass-1 edges per chunk
#define NCH ((EE + CH1 - 1) / CH1)   // 49
#define SCAP 6656        // bucket pass-2 LDS segment capacity

typedef __attribute__((ext_vector_type(8))) _Float16 f16x8;
typedef __attribute__((ext_vector_type(2))) _Float16 h2f;
typedef __attribute__((ext_vector_type(4))) float f32x4;
#define MFMAH(a, b, c) __builtin_amdgcn_mfma_f32_16x16x32_f16(a, b, c, 0, 0, 0)

// ---------------- src-degree histogram (chunked, LDS) -----------------------
__global__ __launch_bounds__(256) void k_hist(const int* __restrict__ edges,
                                              unsigned* __restrict__ hist) {
    __shared__ unsigned bins[RGN / 2];  // 6250 u32 = 25 KB
    int bid = blockIdx.x;
    int r = bid >> 6;              // NRG*HCH = 64 blocks per relation
    int rem = bid & 63;
    int rg = rem >> 4;
    int c = rem & 15;
    int tid = threadIdx.x;
    for (int i = tid; i < RGN / 2; i += 256) bins[i] = 0;
    __syncthreads();
    const int* ea = edges + (size_t)r * 2 * EE + (size_t)c * HEG;  // src side
    int base = rg * RGN;
    for (int e = tid; e < HEG; e += 256) {
        int idx = __builtin_nontemporal_load(&ea[e]) - base;
        if ((unsigned)idx < (unsigned)RGN)
            atomicAdd(&bins[idx >> 1], (idx & 1) ? 65536u : 1u);
    }
    __syncthreads();
    unsigned* ho = hist + ((size_t)(r * NRG + rg) * HCH + c) * (RGN / 2);
    for (int i = tid; i < RGN / 2; i += 256) ho[i] = bins[i];
}

// ---------------- reduce histograms -> ns (fp16) ----------------------------
__global__ void k_sums(const unsigned* __restrict__ hist, __half* __restrict__ nsh) {
    int i = blockIdx.x * blockDim.x + threadIdx.x;
    if (i >= 9 * (NN / 2)) return;
    int r = i / (NN / 2);
    int ps = i - r * (NN / 2);
    int rg = ps / (RGN / 2);
    int slot = ps - rg * (RGN / 2);
    const unsigned* hs = hist + ((size_t)(r * NRG + rg) * HCH) * (RGN / 2) + slot;
    unsigned slo = 0, shi = 0;
#pragma unroll
    for (int c = 0; c < HCH; ++c) {
        unsigned a = hs[(size_t)c * (RGN / 2)];
        slo += a & 0xffffu; shi += a >> 16;
    }
    int n0 = 2 * ps;
    nsh[r * NN + n0]     = slo ? __float2half_rn(rsqrtf((float)slo)) : __half(0.f);
    nsh[r * NN + n0 + 1] = shi ? __float2half_rn(rsqrtf((float)shi)) : __half(0.f);
}

// ---------------- per-bucket edge counts ------------------------------------
__global__ __launch_bounds__(256) void k_bcount(const int* __restrict__ edges,
                                                int* __restrict__ bcount) {
    __shared__ int bins[NBK];
    int bid = blockIdx.x;
    int r = bid / NCH, c = bid - r * NCH;
    int tid = threadIdx.x;
    for (int i = tid; i < NBK; i += 256) bins[i] = 0;
    __syncthreads();
    int e0 = c * CH1, e1 = min(EE, e0 + CH1);
    const int* ed = edges + (size_t)r * 2 * EE + EE;
    for (int e = e0 + tid; e < e1; e += 256)
        atomicAdd(&bins[__builtin_nontemporal_load(&ed[e]) >> 9], 1);
    __syncthreads();
    for (int i = tid; i < NBK; i += 256)
        if (bins[i]) atomicAdd(&bcount[r * NBK + i], bins[i]);
}

// ---------------- scan bucket counts -> bases, gcur seeds, off[NN] ----------
__global__ void k_bscan(const int* __restrict__ bcount, int* __restrict__ bbase,
                        int* __restrict__ gcur, int* __restrict__ off) {
    int r = threadIdx.x;
    if (r >= 9) return;
    int acc = 0;
    for (int b = 0; b < NBK; ++b) {
        bbase[r * (NBK + 1) + b] = acc;
        gcur[r * NBK + b] = acc;
        acc += bcount[r * NBK + b];
    }
    bbase[r * (NBK + 1) + NBK] = acc;
    off[r * (NN + 1) + NN] = acc;   // == EE
}

// ---------------- pass 1: bucket edges by dst>>9, packed u32 ----------------
__global__ __launch_bounds__(256) void k_bucket(const int* __restrict__ edges,
                                                int* __restrict__ gcur,
                                                unsigned* __restrict__ bpairs) {
    __shared__ int hist[NBK];
    __shared__ int sc[128];
    __shared__ int lofs[NBK + 1];
    __shared__ int lcur[NBK];
    __shared__ int gbase[NBK];
    __shared__ unsigned stage[CH1];
    int bid = blockIdx.x;
    int r = bid / NCH, c = bid - r * NCH;
    int tid = threadIdx.x;
    int e0 = c * CH1;
    int e1 = min(EE, e0 + CH1);
    int n = e1 - e0;
    const int* es = edges + (size_t)r * 2 * EE;
    const int* ed = es + EE;

    for (int i = tid; i < NBK; i += 256) hist[i] = 0;
    __syncthreads();
    for (int e = e0 + tid; e < e1; e += 256)
        atomicAdd(&hist[ed[e] >> 9], 1);
    __syncthreads();
    if (tid < 128) sc[tid] = (tid < NBK) ? hist[tid] : 0;
    __syncthreads();
#pragma unroll
    for (int s = 1; s < 128; s <<= 1) {
        int t = 0;
        if (tid < 128 && tid >= s) t = sc[tid - s];
        __syncthreads();
        if (tid < 128 && tid >= s) sc[tid] += t;
        __syncthreads();
    }
    if (tid < NBK) {
        int ex = sc[tid] - hist[tid];
        lofs[tid] = ex;
        lcur[tid] = ex;
        gbase[tid] = atomicAdd(&gcur[r * NBK + tid], hist[tid]);
    }
    if (tid == 0) lofs[NBK] = n;
    __syncthreads();
    for (int e = e0 + tid; e < e1; e += 256) {
        int dst = ed[e];
        int src = es[e];
        int p = atomicAdd(&lcur[dst >> 9], 1);
        stage[p] = ((unsigned)dst << 16) | (unsigned)src;
    }
    __syncthreads();
    unsigned* bp = bpairs + (size_t)r * EE;
    for (int i = tid; i < n; i += 256) {
        int lo = 0, hi = NBK;
        while (hi - lo > 1) {
            int m = (lo + hi) >> 1;
            if (lofs[m] <= i) lo = m; else hi = m;
        }
        bp[gbase[lo] + (i - lofs[lo])] = stage[i];
    }
}

// ---------------- pass 2: per-bucket degrees + offsets + LDS scatter --------
// Writes esn packed {ns_fp16<<16 | src}.
__global__ __launch_bounds__(256) void k_scatter(const unsigned* __restrict__ bpairs,
                                                 const int* __restrict__ bbase,
                                                 const __half* __restrict__ nsh,
                                                 int* __restrict__ off,
                                                 float* __restrict__ nd,
                                                 unsigned* __restrict__ esn) {
    __shared__ int bins[BKW];
    __shared__ int lcur[BKW];
    __shared__ int wsum[4];
    __shared__ unsigned lout[SCAP];
    int bid = blockIdx.x;
    int r = bid / NBK, b = bid - r * NBK;
    int tid = threadIdx.x;
    int d0 = b * BKW;
    int d1 = min(NN, d0 + BKW);
    int nb = d1 - d0;
    int s0 = bbase[r * (NBK + 1) + b];
    int s1 = bbase[r * (NBK + 1) + b + 1];
    int n = s1 - s0;
    for (int i = tid; i < BKW; i += 256) bins[i] = 0;
    __syncthreads();
    const unsigned* bp = bpairs + (size_t)r * EE + s0;
    for (int i = tid; i < n; i += 256)
        atomicAdd(&bins[(int)(bp[i] >> 16) - d0], 1);
    __syncthreads();
    int v0 = bins[2 * tid], v1 = bins[2 * tid + 1];
    int s = v0 + v1;
    int lane = tid & 63, w = tid >> 6;
    int x = s;
#pragma unroll
    for (int sh = 1; sh < 64; sh <<= 1) {
        int y = __shfl_up(x, (unsigned)sh);
        if (lane >= sh) x += y;
    }
    if (lane == 63) wsum[w] = x;
    __syncthreads();
    int wb = 0;
#pragma unroll
    for (int j = 0; j < 3; ++j) wb += (j < w) ? wsum[j] : 0;
    int ex = wb + x - s;      // exclusive prefix for bin 2t
    int* o = off + r * (NN + 1);
    if (2 * tid < nb) {
        o[d0 + 2 * tid] = s0 + ex;
        nd[r * NN + d0 + 2 * tid] = v0 ? rsqrtf((float)v0) : 0.f;
    }
    if (2 * tid + 1 < nb) {
        o[d0 + 2 * tid + 1] = s0 + ex + v0;
        nd[r * NN + d0 + 2 * tid + 1] = v1 ? rsqrtf((float)v1) : 0.f;
    }
    lcur[2 * tid] = ex;
    lcur[2 * tid + 1] = ex + v0;
    __syncthreads();
    const __half* nsr = nsh + (size_t)r * NN;
    unsigned* out = esn + (size_t)r * EE + s0;
    if (n <= SCAP) {
        for (int i = tid; i < n; i += 256) {
            unsigned pr = bp[i];
            int src = (int)(pr & 0xffffu);
            unsigned wbits = (unsigned)__half_as_ushort(nsr[src]);
            int p = atomicAdd(&lcur[(int)(pr >> 16) - d0], 1);
            lout[p] = (wbits << 16) | (unsigned)src;
        }
        __syncthreads();
        for (int i = tid; i < n; i += 256) out[i] = lout[i];
    } else {  // statistically unreachable safety path
        for (int i = tid; i < n; i += 256) {
            unsigned pr = bp[i];
            int src = (int)(pr & 0xffffu);
            unsigned wbits = (unsigned)__half_as_ushort(nsr[src]);
            int p = atomicAdd(&lcur[(int)(pr >> 16) - d0], 1);
            out[p] = (wbits << 16) | (unsigned)src;
        }
    }
}

// ---------------- x -> fp16 conversion ---------------------------------------
__global__ void k_xprep(const float* __restrict__ x0, const float* __restrict__ x1,
                        const float* __restrict__ x2, __half* __restrict__ xh) {
    int i = blockIdx.x * blockDim.x + threadIdx.x;  // float4 index over 3*NN*32
    const int per = NN * 32;
    if (i >= 3 * per) return;
    int tsel = i / per;
    int o = i - tsel * per;
    const float* xp = (tsel == 0) ? x0 : ((tsel == 1) ? x1 : x2);
    float4 v = *reinterpret_cast<const float4*>(xp + (size_t)o * 4);
    __half* dst = xh + (size_t)tsel * NN * 128 + (size_t)o * 4;
    *reinterpret_cast<__half2*>(dst) = __floats2half2_rn(v.x, v.y);
    *reinterpret_cast<__half2*>(dst + 2) = __floats2half2_rn(v.z, v.w);
}

// ---------------- W prep: fp32 [K][N] -> chunk-major fp16 plane -------------
__global__ void k_wprep(const float* __restrict__ W1, const float* __restrict__ W2,
                        __half* __restrict__ whi) {
    int id = blockIdx.x * blockDim.x + threadIdx.x;
    const int total = 2 * 9 * 128 * 128;
    if (id >= total) return;
    int n = id & 127;
    int k = (id >> 7) & 127;
    int rl = id >> 14;  // layer*9 + r
    const float* W = (rl < 9) ? W1 : W2;
    int r = (rl < 9) ? rl : rl - 9;
    float f = W[((size_t)r * 128 + k) * 128 + n];
    size_t oidx = (((size_t)rl * 4 + (k >> 5)) * 128 + n) * 32 + (k & 31);
    whi[oidx] = __float2half_rn(f);
}

// ---------------- aggregation: ALL 9 relations in one launch -----------------
// grid 112500 = 3 src-group ranges x (3 rels x 12500). Blocks in a range
// interleave that range's 3 relations (%3) -> concurrent blocks share ONE src
// plane (XCD-L2 locality); ranges run back-to-back. Body: 4 edge-slots x 16
// col-lanes, A/B batches always, C/D behind wave-uniform branch.
struct AggT {
    const __half* xin;
    const int* off;
    const unsigned* esn;
    const float* nd;
    __half* A;
};
struct Agg9 { AggT t[9]; };

__global__ __launch_bounds__(256) void k_agg9(Agg9 a) {
    int bid = blockIdx.x;
    int range = bid / 37500;           // src group 0..2
    int sub = bid - range * 37500;
    int task = range * 3 + (sub % 3);
    int wave = (sub / 3) * 4 + (threadIdx.x >> 6);
    int lane = threadIdx.x & 63;
    if (wave >= NN) return;
    AggT t = a.t[task];
    int g = lane >> 4;       // edge slot 0..3
    int c = lane & 15;       // column group: cols c*8 .. c*8+7
    int e0 = t.off[wave], e1 = t.off[wave + 1];
    const __half* xin = t.xin;
    const unsigned* esn = t.esn;
    const h2f zz = {(_Float16)0.f, (_Float16)0.f};
    h2f accA[4] = {zz, zz, zz, zz};
    h2f accB[4] = {zz, zz, zz, zz};
    h2f accC[4] = {zz, zz, zz, zz};
    h2f accD[4] = {zz, zz, zz, zz};
    for (int e = e0; e < e1; e += 16) {
        // ---- batches A,B: edges e .. e+7 ----
        {
            int ea = e + g, eb = e + 4 + g;
            bool va = ea < e1, vb = eb < e1;
            unsigned ua = esn[va ? ea : e];
            unsigned ub = esn[vb ? eb : e];
            int sa = ua & 0xffffu, sb = ub & 0xffffu;
            _Float16 wa = va ? __builtin_bit_cast(_Float16, (unsigned short)(ua >> 16)) : (_Float16)0.f;
            _Float16 wb = vb ? __builtin_bit_cast(_Float16, (unsigned short)(ub >> 16)) : (_Float16)0.f;
            h2f wav = {wa, wa}, wbv = {wb, wb};
            float4 ra = *reinterpret_cast<const float4*>(xin + (size_t)sa * 128 + c * 8);
            float4 rb = *reinterpret_cast<const float4*>(xin + (size_t)sb * 128 + c * 8);
            const h2f* pa = reinterpret_cast<const h2f*>(&ra);
            const h2f* pb = reinterpret_cast<const h2f*>(&rb);
#pragma unroll
            for (int j = 0; j < 4; ++j) {
                accA[j] = wav * pa[j] + accA[j];   // v_pk_fma_f16
                accB[j] = wbv * pb[j] + accB[j];
            }
        }
        // ---- batches C,D: edges e+8 .. e+15 (wave-uniform skip) ----
        if (e + 8 < e1) {
            int ec = e + 8 + g, ed = e + 12 + g;
            bool vc = ec < e1, vd = ed < e1;
            unsigned uc = esn[vc ? ec : e];
            unsigned ud = esn[vd ? ed : e];
            int sc_ = uc & 0xffffu, sd = ud & 0xffffu;
            _Float16 wc = vc ? __builtin_bit_cast(_Float16, (unsigned short)(uc >> 16)) : (_Float16)0.f;
            _Float16 wd = vd ? __builtin_bit_cast(_Float16, (unsigned short)(ud >> 16)) : (_Float16)0.f;
            h2f wcv = {wc, wc}, wdv = {wd, wd};
            float4 rc = *reinterpret_cast<const float4*>(xin + (size_t)sc_ * 128 + c * 8);
            float4 rd = *reinterpret_cast<const float4*>(xin + (size_t)sd * 128 + c * 8);
            const h2f* pc = reinterpret_cast<const h2f*>(&rc);
            const h2f* pd = reinterpret_cast<const h2f*>(&rd);
#pragma unroll
            for (int j = 0; j < 4; ++j) {
                accC[j] = wcv * pc[j] + accC[j];
                accD[j] = wdv * pd[j] + accD[j];
            }
        }
    }
    float acc[8];
#pragma unroll
    for (int j = 0; j < 4; ++j) {
        acc[2 * j]     = ((float)accA[j][0] + (float)accB[j][0]) +
                         ((float)accC[j][0] + (float)accD[j][0]);
        acc[2 * j + 1] = ((float)accA[j][1] + (float)accB[j][1]) +
                         ((float)accC[j][1] + (float)accD[j][1]);
    }
#pragma unroll
    for (int j = 0; j < 8; ++j) {
        acc[j] += __shfl_xor(acc[j], 16);
        acc[j] += __shfl_xor(acc[j], 32);
    }
    if (g == 0) {
        float nr = t.nd[wave];
        f16x8 hv;
#pragma unroll
        for (int j = 0; j < 8; ++j) hv[j] = (_Float16)(acc[j] * nr);
        *reinterpret_cast<f16x8*>(t.A + (size_t)wave * 128 + c * 8) = hv;
    }
}

// ---------------- merged f16 MFMA GEMM: H = relu(sum_s A_s @ W_s + b_s) -----
// One launch per dst plane; single writer -> pure STORE, summed biases.
struct GArg {
    const __half* A[4];
    const __half* W[4];
    const float* b[4];
};

template <int NS>
__global__ __launch_bounds__(256) void k_gemmM(GArg ga, __half* __restrict__ H) {
    int tid = threadIdx.x;
    int w = tid >> 6, lane = tid & 63;
    int row0 = blockIdx.x * 64;
    int colbase = w * 32;
    int r16 = lane & 15;
    int koff = (lane >> 4) * 8;

    f32x4 acc[4][2];
#pragma unroll
    for (int rt = 0; rt < 4; ++rt)
#pragma unroll
        for (int nt = 0; nt < 2; ++nt)
            acc[rt][nt] = f32x4{0.f, 0.f, 0.f, 0.f};

#pragma unroll
    for (int s = 0; s < NS; ++s) {
        const __half* A = ga.A[s];
        const __half* w_h = ga.W[s];
#pragma unroll
        for (int c = 0; c < 4; ++c) {
            int kbase = c * 32 + koff;
            f16x8 av[4], bh[2];
#pragma unroll
            for (int rt = 0; rt < 4; ++rt) {
                int rr = rt * 16 + r16;
                int rc = (row0 + rr < NN) ? rr : 0;
                av[rt] = *reinterpret_cast<const f16x8*>(
                    A + ((size_t)(row0 + rc)) * 128 + kbase);
            }
#pragma unroll
            for (int nt = 0; nt < 2; ++nt) {
                int col = colbase + nt * 16 + r16;
                size_t widx = ((size_t)c * 128 + col) * 32 + koff;
                bh[nt] = *reinterpret_cast<const f16x8*>(w_h + widx);
            }
#pragma unroll
            for (int rt = 0; rt < 4; ++rt)
#pragma unroll
                for (int nt = 0; nt < 2; ++nt)
                    acc[rt][nt] = MFMAH(av[rt], bh[nt], acc[rt][nt]);
        }
    }

    int orow = (lane >> 4) * 4;
#pragma unroll
    for (int nt = 0; nt < 2; ++nt) {
        int col = colbase + nt * 16 + r16;
        float bias = 0.f;
#pragma unroll
        for (int s = 0; s < NS; ++s) bias += ga.b[s][col];
#pragma unroll
        for (int rt = 0; rt < 4; ++rt) {
#pragma unroll
            for (int j = 0; j < 4; ++j) {
                int grow = row0 + rt * 16 + orow + j;
                if (grow < NN) {
                    __half* hp = H + (size_t)grow * 128 + col;
                    float v = fmaxf(acc[rt][nt][j] + bias, 0.f);
                    *hp = __float2half_rn(v);
                }
            }
        }
    }
}

// ---------------- classifier: out = relu(H_fp16) @ Wc + bc ------------------
// (H already relu'd by GEMM epilogue; fmaxf kept — idempotent, safe.)
__global__ __launch_bounds__(256) void k_classifier(const __half* __restrict__ H,
                                                    const float* __restrict__ Wc,
                                                    const float* __restrict__ bc,
                                                    float* __restrict__ out) {
    __shared__ float sW[128 * 16];
    __shared__ float sb[16];
    int tid = threadIdx.x;
#pragma unroll
    for (int i = tid; i < 2048; i += 256) sW[i] = Wc[i];
    if (tid < 16) sb[tid] = bc[tid];
    __syncthreads();
    int node = blockIdx.x * 64 + (tid >> 2);
    if (node >= 3 * NN) return;
    int cg = (tid & 3) << 2;
    const __half* h = H + (size_t)node * 128;
    float acc0 = 0.f, acc1 = 0.f, acc2 = 0.f, acc3 = 0.f;
#pragma unroll 2
    for (int k0 = 0; k0 < 128; k0 += 8) {
        float4 raw = *reinterpret_cast<const float4*>(h + k0);  // 8 halves
        const __half2* hp2 = reinterpret_cast<const __half2*>(&raw);
#pragma unroll
        for (int jj = 0; jj < 4; ++jj) {
            float2 f = __half22float2(hp2[jj]);
            float a;
            a = fmaxf(f.x, 0.f);
            { float4 wv = *reinterpret_cast<const float4*>(&sW[(k0 + 2 * jj) * 16 + cg]);
              acc0 = fmaf(a, wv.x, acc0); acc1 = fmaf(a, wv.y, acc1);
              acc2 = fmaf(a, wv.z, acc2); acc3 = fmaf(a, wv.w, acc3); }
            a = fmaxf(f.y, 0.f);
            { float4 wv = *reinterpret_cast<const float4*>(&sW[(k0 + 2 * jj + 1) * 16 + cg]);
              acc0 = fmaf(a, wv.x, acc0); acc1 = fmaf(a, wv.y, acc1);
              acc2 = fmaf(a, wv.z, acc2); acc3 = fmaf(a, wv.w, acc3); }
        }
    }
    float4 o = make_float4(acc0 + sb[cg], acc1 + sb[cg + 1],
                           acc2 + sb[cg + 2], acc3 + sb[cg + 3]);
    *reinterpret_cast<float4*>(out + (size_t)node * 16 + cg) = o;
}

// ---------------------------------------------------------------------------
extern "C" void kernel_launch(void* const* d_in, const int* in_sizes, int n_in,
                              void* d_out, int out_size, void* d_ws, size_t ws_size,
                              hipStream_t stream) {
    const float* x0 = (const float*)d_in[0];
    const float* x1 = (const float*)d_in[1];
    const float* x2 = (const float*)d_in[2];
    const float* W1 = (const float*)d_in[3];
    const float* b1 = (const float*)d_in[4];
    const float* W2 = (const float*)d_in[5];
    const float* b2 = (const float*)d_in[6];
    const float* Wc = (const float*)d_in[7];
    const float* bc = (const float*)d_in[8];
    const int* edges = (const int*)d_in[9];

    // ---- workspace carve-up with overlays (~212 MB peak) ----
    char* p = (char*)d_ws;
    auto alloc = [&](size_t bytes) -> void* {
        void* r = (void*)p;
        p += (bytes + 255) & ~(size_t)255;
        return r;
    };
    __half* h2h = (__half*)alloc((size_t)3 * NN * 128 * sizeof(__half));  // 38.4 MB
    // aliases inside h2h: hist [k_hist,k_sums), bpairs [k_bucket,k_scatter),
    // A-slots 6..8 during LAYER 1 (h2h written only by layer-2 GEMM).
    unsigned* hist = (unsigned*)h2h;
    unsigned* bpairs = (unsigned*)h2h;
    __half* xh  = (__half*)alloc((size_t)3 * NN * 128 * sizeof(__half));  // 38.4 MB
    __half* h1h = (__half*)alloc((size_t)3 * NN * 128 * sizeof(__half));  // 38.4 MB
    __half* A6  = (__half*)alloc((size_t)6 * NN * 128 * sizeof(__half));  // 76.8 MB
    int* off = (int*)alloc((size_t)9 * (NN + 1) * sizeof(int));
    __half* nsh = (__half*)alloc((size_t)9 * NN * sizeof(__half));
    float* nd = (float*)alloc((size_t)9 * NN * sizeof(float));
    unsigned* esn = (unsigned*)alloc((size_t)9 * EE * sizeof(unsigned));  // 14.4 MB
    __half* whi = (__half*)alloc((size_t)2 * 9 * 128 * 128 * sizeof(__half));
    int* gcur = (int*)alloc((size_t)9 * NBK * sizeof(int));
    int* bcount = (int*)alloc((size_t)9 * NBK * sizeof(int));
    int* bbase = (int*)alloc((size_t)9 * (NBK + 1) * sizeof(int));
    const __half* xph[3] = {xh, xh + (size_t)NN * 128, xh + (size_t)2 * NN * 128};

    // ---- CSR build + input/weight prep (reused by both layers) ----
    k_hist<<<9 * NRG * HCH, 256, 0, stream>>>(edges, hist);
    k_xprep<<<(3 * NN * 32 + 255) / 256, 256, 0, stream>>>(x0, x1, x2, xh);
    k_sums<<<(9 * (NN / 2) + 255) / 256, 256, 0, stream>>>(hist, nsh);
    hipMemsetAsync(bcount, 0, (size_t)9 * NBK * sizeof(int), stream);
    k_bcount<<<9 * NCH, 256, 0, stream>>>(edges, bcount);
    k_bscan<<<1, 64, 0, stream>>>(bcount, bbase, gcur, off);
    k_bucket<<<9 * NCH, 256, 0, stream>>>(edges, gcur, bpairs);
    k_scatter<<<9 * NBK, 256, 0, stream>>>(bpairs, bbase, nsh, off, nd, esn);
    k_wprep<<<(2 * 9 * 128 * 128 + 255) / 256, 256, 0, stream>>>(W1, W2, whi);

    const int gemm_blocks = (NN + 63) / 64;   // 782
    auto wp = [&](int layer, int r) { return (size_t)(layer * 9 + r) * 16384; };

    // task order (slot j -> relation): grouped by src type
    const int TASKREL[9] = {0, 3, 6,  1, 2, 8,  4, 5, 7};
    // dst planes: plane0 <- rels {3,6,2,5} ; plane1 <- {8,4} ; plane2 <- {0,1,7}

    for (int L = 0; L < 2; ++L) {
        const float* b = (L == 0) ? b1 : b2;
        __half* hout = (L == 0) ? h1h : h2h;
        // A-slot pointers: 0..5 in A6; 6..8 overlay h2h (L0) / xh (L1)
        __half* ovl = (L == 0) ? h2h : xh;
        __half* P[9];
        for (int j = 0; j < 6; ++j) P[j] = A6 + (size_t)j * NN * 128;
        for (int j = 6; j < 9; ++j) P[j] = ovl + (size_t)(j - 6) * NN * 128;

        // ---- one agg launch: all 9 relations ----
        Agg9 a9;
        for (int j = 0; j < 9; ++j) {
            int r = TASKREL[j];
            const __half* xin;
            if (L == 0) xin = xph[j / 3];
            else        xin = h1h + (size_t)(j / 3) * NN * 128;
            a9.t[j] = AggT{xin, off + r * (NN + 1), esn + (size_t)r * EE,
                           nd + r * NN, P[j]};
        }
        k_agg9<<<112500, 256, 0, stream>>>(a9);

        // ---- three merged GEMMs (single writer per plane) ----
        // plane0: rels (3,6,2,5) -> slots (1,2,4,7)
        {
            GArg ga;
            const int rs[4] = {3, 6, 2, 5};
            const int sl[4] = {1, 2, 4, 7};
            for (int s = 0; s < 4; ++s) {
                ga.A[s] = P[sl[s]];
                ga.W[s] = whi + wp(L, rs[s]);
                ga.b[s] = b + rs[s] * 128;
            }
            k_gemmM<4><<<gemm_blocks, 256, 0, stream>>>(ga, hout + (size_t)0 * NN * 128);
        }
        // plane1: rels (8,4) -> slots (5,6)
        {
            GArg ga;
            const int rs[2] = {8, 4};
            const int sl[2] = {5, 6};
            for (int s = 0; s < 2; ++s) {
                ga.A[s] = P[sl[s]];
                ga.W[s] = whi + wp(L, rs[s]);
                ga.b[s] = b + rs[s] * 128;
            }
            ga.A[2] = ga.A[3] = ga.A[0]; ga.W[2] = ga.W[3] = ga.W[0];
            ga.b[2] = ga.b[3] = ga.b[0];
            k_gemmM<2><<<gemm_blocks, 256, 0, stream>>>(ga, hout + (size_t)1 * NN * 128);
        }
        // plane2: rels (0,1,7) -> slots (0,3,8)
        {
            GArg ga;
            const int rs[3] = {0, 1, 7};
            const int sl[3] = {0, 3, 8};
            for (int s = 0; s < 3; ++s) {
                ga.A[s] = P[sl[s]];
                ga.W[s] = whi + wp(L, rs[s]);
                ga.b[s] = b + rs[s] * 128;
            }
            ga.A[3] = ga.A[0]; ga.W[3] = ga.W[0]; ga.b[3] = ga.b[0];
            k_gemmM<3><<<gemm_blocks, 256, 0, stream>>>(ga, hout + (size_t)2 * NN * 128);
        }
    }

    // ---- classifier: out = relu(h2h) @ Wc + bc ----
    k_classifier<<<(3 * NN + 63) / 64, 256, 0, stream>>>(h2h, Wc, bc, (float*)d_out);
}